// Round 4
// baseline (91.118 us; speedup 1.0000x reference)
//
#include <hip/hip_runtime.h>

// TemperatureScaler: piecewise-linear temperature scaling of logits.
// out = T[bin]*x + b[bin],  bin = #{sorted_thr < x},  b = c_pad - T*thr_pad
// B=64, V=128000 -> 8,192,000 fp32 elements. Pure streaming, memory-bound.
//
// R4: same as R3 but with a native clang vector type (ext_vector_type(4))
// for the streamed data — __builtin_nontemporal_load/store rejects HIP's
// float4 class type (R3 compile failure). (a) 2-value (t,b) select cascade:
// 22 VALU ops/elem vs 30; (b) nontemporal ld/st (zero-reuse streams, 64MB
// traffic vs 32MB aggregate L2 — skip the thrash).

#define PIECES 8
#define NTHR (PIECES - 1)
#define TEMP_CLAMP_MIN 1e-4f

typedef float v4f __attribute__((ext_vector_type(4)));

struct Params {
    float T[PIECES];   // clamped temperatures (slope per bin)
    float tp[PIECES];  // thr_pad: [0, thr_sorted...] (cascade keys)
    float bb[PIECES];  // intercept per bin: c_pad - T*thr_pad
};

__device__ __forceinline__ Params make_params(const float* __restrict__ temperature,
                                              const float* __restrict__ thresholds) {
    Params P;
    float thr[NTHR];
    #pragma unroll
    for (int j = 0; j < PIECES; ++j) P.T[j] = fmaxf(temperature[j], TEMP_CLAMP_MIN);
    #pragma unroll
    for (int j = 0; j < NTHR; ++j) thr[j] = thresholds[j];
    // branch-free bubble sort, 21 compare-exchanges (matches jnp.sort; actual
    // input is linspace-sorted so this is an identity, but cheap & uniform)
    #pragma unroll
    for (int i = 0; i < NTHR - 1; ++i) {
        #pragma unroll
        for (int j = 0; j < NTHR - 1 - i; ++j) {
            float lo = fminf(thr[j], thr[j + 1]);
            float hi = fmaxf(thr[j], thr[j + 1]);
            thr[j] = lo; thr[j + 1] = hi;
        }
    }
    // continuity constants c = cumsum(diff(pad(thr,0)) * T[:-1]);
    // intercept b[k] = c_pad[k] - T[k]*tp[k]  (y = T*x + b per bin)
    float prev = 0.f, acc = 0.f;
    P.tp[0] = 0.f; P.bb[0] = 0.f;
    #pragma unroll
    for (int k = 0; k < NTHR; ++k) {
        acc += (thr[k] - prev) * P.T[k];
        prev = thr[k];
        P.tp[k + 1] = thr[k];
        P.bb[k + 1] = fmaf(-P.T[k + 1], thr[k], acc);
    }
    return P;
}

__device__ __forceinline__ float apply1(const Params& P, float x) {
    // searchsorted side='left': bin = #{thr < x}. tp sorted ascending ->
    // (x > tp[j]) is a monotone prefix predicate; last true j wins.
    float t = P.T[0], b = P.bb[0];
    #pragma unroll
    for (int j = 1; j < PIECES; ++j) {
        bool gt = x > P.tp[j];
        t = gt ? P.T[j] : t;
        b = gt ? P.bb[j] : b;
    }
    return fmaf(t, x, b);
}

__device__ __forceinline__ v4f apply4(const Params& P, v4f v) {
    v4f r;
    r.x = apply1(P, v.x);
    r.y = apply1(P, v.y);
    r.z = apply1(P, v.z);
    r.w = apply1(P, v.w);
    return r;
}

__global__ __launch_bounds__(256) void temp_scale_kernel(
    const v4f* __restrict__ x4,
    v4f* __restrict__ out4,
    const float* __restrict__ temperature,
    const float* __restrict__ thresholds,
    int n4, int n_tail, const float* __restrict__ x_tail_base,
    float* __restrict__ out_tail_base)
{
    const Params P = make_params(temperature, thresholds);

    const int stride = gridDim.x * blockDim.x;
    const int tid = blockIdx.x * blockDim.x + threadIdx.x;

    int i = tid;
    // 4-deep batched main loop: 4 independent 16B nt-loads in flight
    for (; i + 3 * stride < n4; i += 4 * stride) {
        v4f a = __builtin_nontemporal_load(&x4[i]);
        v4f b = __builtin_nontemporal_load(&x4[i + stride]);
        v4f c = __builtin_nontemporal_load(&x4[i + 2 * stride]);
        v4f d = __builtin_nontemporal_load(&x4[i + 3 * stride]);
        __builtin_nontemporal_store(apply4(P, a), &out4[i]);
        __builtin_nontemporal_store(apply4(P, b), &out4[i + stride]);
        __builtin_nontemporal_store(apply4(P, c), &out4[i + 2 * stride]);
        __builtin_nontemporal_store(apply4(P, d), &out4[i + 3 * stride]);
    }
    for (; i < n4; i += stride)
        __builtin_nontemporal_store(apply4(P, __builtin_nontemporal_load(&x4[i])), &out4[i]);

    // scalar tail (n % 4) — empty for 8,192,000 but kept for safety
    if (tid < n_tail) out_tail_base[tid] = apply1(P, x_tail_base[tid]);
}

extern "C" void kernel_launch(void* const* d_in, const int* in_sizes, int n_in,
                              void* d_out, int out_size, void* d_ws, size_t ws_size,
                              hipStream_t stream) {
    const float* logits      = (const float*)d_in[0];   // (B, V) fp32
    const float* temperature = (const float*)d_in[1];   // (1, PIECES) fp32
    const float* thresholds  = (const float*)d_in[2];   // (1, NTHR) fp32
    float* out = (float*)d_out;

    const int n = in_sizes[0];
    const int n4 = n / 4;
    const int n_tail = n - n4 * 4;

    // 2000 blocks x 256 thr = 512,000 threads; n4 = 2,048,000 -> exactly 4
    // float4 per thread. ~8 blocks/CU resident at this VGPR count.
    const int block = 256;
    int grid = 2000;
    int need = (n4 + block - 1) / block;
    if (need < grid) grid = need;
    if (grid < 1) grid = 1;

    temp_scale_kernel<<<grid, block, 0, stream>>>(
        (const v4f*)logits, (v4f*)out, temperature, thresholds,
        n4, n_tail, logits + (size_t)n4 * 4, out + (size_t)n4 * 4);
}

// Round 5
// 86.040 us; speedup vs baseline: 1.0590x; 1.0590x over previous
//
#include <hip/hip_runtime.h>

// TemperatureScaler: piecewise-linear temperature scaling of logits.
// out = T[bin]*x + b[bin],  bin = #{sorted_thr < x},  b = c_pad - T*thr_pad
// B=64, V=128000 -> 8,192,000 fp32 elements. Pure streaming, memory-bound.
//
// R5: R2's plain (cached) ld/st — the best-measured config — plus R4's
// 2-value (t,b) select cascade (15 VALU/elem select + 1 fma, vs 22 for the
// 3-value form). Nontemporal ld/st reverted: it was the one change present
// in the slowest run (91.1 vs 86.9 µs); nt stores' no-allocate path did not
// pay on the write stream. R1/R2/R4 all land 89±2 µs -> total is dominated
// by harness poison/restore fills (~43+6+11 µs visible in rocprof); kernel
// is near its 10.4 µs HBM floor (65.5 MB @ 6.3 TB/s).

#define PIECES 8
#define NTHR (PIECES - 1)
#define TEMP_CLAMP_MIN 1e-4f

typedef float v4f __attribute__((ext_vector_type(4)));

struct Params {
    float T[PIECES];   // clamped temperatures (slope per bin)
    float tp[PIECES];  // thr_pad: [0, thr_sorted...] (cascade keys)
    float bb[PIECES];  // intercept per bin: c_pad - T*thr_pad
};

__device__ __forceinline__ Params make_params(const float* __restrict__ temperature,
                                              const float* __restrict__ thresholds) {
    Params P;
    float thr[NTHR];
    #pragma unroll
    for (int j = 0; j < PIECES; ++j) P.T[j] = fmaxf(temperature[j], TEMP_CLAMP_MIN);
    #pragma unroll
    for (int j = 0; j < NTHR; ++j) thr[j] = thresholds[j];
    // branch-free bubble sort, 21 compare-exchanges (matches jnp.sort; actual
    // input is linspace-sorted so this is an identity, but cheap & uniform)
    #pragma unroll
    for (int i = 0; i < NTHR - 1; ++i) {
        #pragma unroll
        for (int j = 0; j < NTHR - 1 - i; ++j) {
            float lo = fminf(thr[j], thr[j + 1]);
            float hi = fmaxf(thr[j], thr[j + 1]);
            thr[j] = lo; thr[j + 1] = hi;
        }
    }
    // continuity constants c = cumsum(diff(pad(thr,0)) * T[:-1]);
    // intercept b[k] = c_pad[k] - T[k]*tp[k]  (y = T*x + b per bin)
    float prev = 0.f, acc = 0.f;
    P.tp[0] = 0.f; P.bb[0] = 0.f;
    #pragma unroll
    for (int k = 0; k < NTHR; ++k) {
        acc += (thr[k] - prev) * P.T[k];
        prev = thr[k];
        P.tp[k + 1] = thr[k];
        P.bb[k + 1] = fmaf(-P.T[k + 1], thr[k], acc);
    }
    return P;
}

__device__ __forceinline__ float apply1(const Params& P, float x) {
    // searchsorted side='left': bin = #{thr < x}. tp sorted ascending ->
    // (x > tp[j]) is a monotone prefix predicate; last true j wins.
    float t = P.T[0], b = P.bb[0];
    #pragma unroll
    for (int j = 1; j < PIECES; ++j) {
        bool gt = x > P.tp[j];
        t = gt ? P.T[j] : t;
        b = gt ? P.bb[j] : b;
    }
    return fmaf(t, x, b);
}

__device__ __forceinline__ v4f apply4(const Params& P, v4f v) {
    v4f r;
    r.x = apply1(P, v.x);
    r.y = apply1(P, v.y);
    r.z = apply1(P, v.z);
    r.w = apply1(P, v.w);
    return r;
}

__global__ __launch_bounds__(256) void temp_scale_kernel(
    const v4f* __restrict__ x4,
    v4f* __restrict__ out4,
    const float* __restrict__ temperature,
    const float* __restrict__ thresholds,
    int n4, int n_tail, const float* __restrict__ x_tail_base,
    float* __restrict__ out_tail_base)
{
    const Params P = make_params(temperature, thresholds);

    const int stride = gridDim.x * blockDim.x;
    const int tid = blockIdx.x * blockDim.x + threadIdx.x;

    int i = tid;
    // 4-deep batched main loop: 4 independent 16B loads in flight per thread
    for (; i + 3 * stride < n4; i += 4 * stride) {
        v4f a = x4[i];
        v4f b = x4[i + stride];
        v4f c = x4[i + 2 * stride];
        v4f d = x4[i + 3 * stride];
        out4[i]              = apply4(P, a);
        out4[i + stride]     = apply4(P, b);
        out4[i + 2 * stride] = apply4(P, c);
        out4[i + 3 * stride] = apply4(P, d);
    }
    for (; i < n4; i += stride) out4[i] = apply4(P, x4[i]);

    // scalar tail (n % 4) — empty for 8,192,000 but kept for safety
    if (tid < n_tail) out_tail_base[tid] = apply1(P, x_tail_base[tid]);
}

extern "C" void kernel_launch(void* const* d_in, const int* in_sizes, int n_in,
                              void* d_out, int out_size, void* d_ws, size_t ws_size,
                              hipStream_t stream) {
    const float* logits      = (const float*)d_in[0];   // (B, V) fp32
    const float* temperature = (const float*)d_in[1];   // (1, PIECES) fp32
    const float* thresholds  = (const float*)d_in[2];   // (1, NTHR) fp32
    float* out = (float*)d_out;

    const int n = in_sizes[0];
    const int n4 = n / 4;
    const int n_tail = n - n4 * 4;

    // 2000 blocks x 256 thr = 512,000 threads; n4 = 2,048,000 -> exactly 4
    // float4 per thread. ~8 blocks/CU resident at this VGPR count.
    const int block = 256;
    int grid = 2000;
    int need = (n4 + block - 1) / block;
    if (need < grid) grid = need;
    if (grid < 1) grid = 1;

    temp_scale_kernel<<<grid, block, 0, stream>>>(
        (const v4f*)logits, (v4f*)out, temperature, thresholds,
        n4, n_tail, logits + (size_t)n4 * 4, out + (size_t)n4 * 4);
}